// Round 11
// baseline (4132.203 us; speedup 1.0000x reference)
//
#include <hip/hip_runtime.h>

#define B_ 256
#define T_ 80
#define IN_ 39
#define H_ 256
#define G_ 1024
#define L_ 5
#define NCHK 6          // batch chunks per layer group
#define NSL 8           // unit slices per layer group (32 units x 4 gates each)

#define HBUF_FLOATS (B_ * T_ * H_)        // 5,242,880 (20 MB)
#define HX_FLOATS   (L_ * 4 * B_ * H_)    // 1,310,720 (5 MB): ring hx[l][slot][b][u]
#define FLG_INTS    (L_ * NCHK * 32)      // one 128B line per (l,c); words 0..7 = slices

// LDS plan (dynamic): sH[43*512] | sG[43*128] | cL[43*32] | sB[128]
#define SH_OFF 0
#define SG_OFF (43 * 512)
#define CL_OFF (SG_OFF + 43 * 128)
#define SB_OFF (CL_OFF + 43 * 32)
#define SMEM_FLOATS (SB_OFF + 128)        // 29,024 floats = 116,096 B

#define AG __HIP_MEMORY_SCOPE_AGENT

__device__ __forceinline__ float sigm(float x) { return 1.0f / (1.0f + expf(-x)); }

// ---- wavefront kernel: 240 blocks = 5 layers x 6 chunks x 8 slices ----
// Block (l,c,s): owns gate rows [s*32*?]: rows g*256 + s*32 + uu (g=0..3,
// uu=0..31) of layer l, batches [c*256/6, (c+1)*256/6). W slice (both
// matrices) in VGPRs. Per step t: gates = Wih.h_in(t) + Whh.h(l,t-1) + b.
// h exchanged via 4-slot MALL ring + per-slice flag stores (r9 scheme).
// Dep edges: intra (t-1), inter (l-1,t), ring-gate (l+1,t-4) -> DAG, and all
// 240 blocks are co-resident (1/CU, LDS-bound) -> no deadlock.
extern "C" __global__ void __launch_bounds__(512, 2)
wave_kernel(const float* __restrict__ x,
            const float* __restrict__ Wih0, const float* __restrict__ Wihr,
            const float* __restrict__ Whh,
            const float* __restrict__ bih, const float* __restrict__ bhh,
            float* __restrict__ hbuf, float* __restrict__ hx,
            int* __restrict__ flg)
{
    extern __shared__ float smem[];
    float* sH = smem + SH_OFF;   // [nb][512] : concat [h_in(256) | h_prev(256)]
    float* sG = smem + SG_OFF;   // [nb][128] : reduced gate pre-activations
    float* cL = smem + CL_OFF;   // [nb][32]  : cell state (persists across t)
    float* sB = smem + SB_OFF;   // [128]     : bias for this slice

    const int tid = threadIdx.x;
    const int bid = blockIdx.x;
    const int l = bid / (NCHK * NSL);
    const int r = bid % (NCHK * NSL);
    const int c = r >> 3;
    const int s = r & 7;

    const int b0 = (c * B_) / NCHK;
    const int b1 = ((c + 1) * B_) / NCHK;
    const int nb = b1 - b0;                  // 42 or 43

    const int wv = tid >> 6;
    const int lane = tid & 63;
    const int kq = (lane >> 4) & 3;          // K-quarter: 0,1=input side; 2,3=recurrent
    const int gr = wv * 16 + (lane & 15);    // gate-row 0..127 within slice
    const int g  = gr >> 5, uu = gr & 31;
    const int grow = g * 256 + s * 32 + uu;  // global gate row in [0,1024)

    // ---- W fragment into registers: 128 consecutive K entries of row grow ----
    float4 wreg[32];
    if (kq >= 2) {
        const float* wsrc = Whh + ((size_t)l * G_ + grow) * H_ + (size_t)(kq - 2) * 128;
        #pragma unroll
        for (int i = 0; i < 32; ++i) wreg[i] = *(const float4*)(wsrc + i * 4);
    } else if (l == 0) {
        const float* wsrc = Wih0 + (size_t)grow * IN_;
        #pragma unroll
        for (int i = 0; i < 32; ++i) {
            float v0 = 0.f, v1 = 0.f, v2 = 0.f, v3 = 0.f;
            const int k = kq * 128 + i * 4;
            if (k + 0 < IN_) v0 = wsrc[k + 0];
            if (k + 1 < IN_) v1 = wsrc[k + 1];
            if (k + 2 < IN_) v2 = wsrc[k + 2];
            if (k + 3 < IN_) v3 = wsrc[k + 3];
            wreg[i] = make_float4(v0, v1, v2, v3);
        }
    } else {
        const float* wsrc = Wihr + (size_t)(l - 1) * G_ * H_
                          + (size_t)grow * H_ + (size_t)kq * 128;
        #pragma unroll
        for (int i = 0; i < 32; ++i) wreg[i] = *(const float4*)(wsrc + i * 4);
    }

    if (tid < 128)
        sB[tid] = bih[l * G_ + (tid >> 5) * 256 + s * 32 + (tid & 31)]
                + bhh[l * G_ + (tid >> 5) * 256 + s * 32 + (tid & 31)];
    for (int i = tid; i < nb * 32; i += 512) cL[i] = 0.0f;

    const unsigned long long* hx64 = (const unsigned long long*)hx;
    const float4* sH4 = (const float4*)sH;

    for (int t = 0; t < T_; ++t) {
        // ---- polls (24 scout threads; flag value = published cell + 1) ----
        if (tid < 24) {
            const int which = tid >> 3, sp = tid & 7;
            const int* fp = nullptr; int tgt = 0;
            if (which == 0) {
                if (t > 0) { fp = flg + (l * NCHK + c) * 32 + sp; tgt = t; }
            } else if (which == 1) {
                if (l > 0) { fp = flg + ((l - 1) * NCHK + c) * 32 + sp; tgt = t + 1; }
            } else {
                if (l < L_ - 1 && t >= 4) { fp = flg + ((l + 1) * NCHK + c) * 32 + sp; tgt = t - 3; }
            }
            if (fp) {
                while (__hip_atomic_load(fp, __ATOMIC_RELAXED, AG) < tgt)
                    __builtin_amdgcn_s_sleep(1);
            }
        }
        __syncthreads();

        // ---- gather h_in (K 0..255) ----
        if (l == 0) {
            for (int i = tid; i < nb * 256; i += 512) {
                const int bb = i >> 8, u = i & 255;
                sH[bb * 512 + u] = (u < IN_)
                    ? x[((size_t)(b0 + bb) * T_ + t) * IN_ + u] : 0.0f;
            }
        } else {
            const size_t base64 = (size_t)((l - 1) * 4 + (t & 3)) * B_ * 128;
            for (int i = tid; i < nb * 128; i += 512) {
                const int bb = i >> 7, up = i & 127;
                unsigned long long v = __hip_atomic_load(
                    hx64 + base64 + (size_t)(b0 + bb) * 128 + up, __ATOMIC_RELAXED, AG);
                *(float2*)&sH[bb * 512 + up * 2] =
                    make_float2(__uint_as_float((unsigned)v),
                                __uint_as_float((unsigned)(v >> 32)));
            }
        }
        // ---- gather h_prev (K 256..511) ----
        if (t == 0) {
            for (int i = tid; i < nb * 256; i += 512) {
                const int bb = i >> 8, u = i & 255;
                sH[bb * 512 + 256 + u] = 0.0f;
            }
        } else {
            const size_t base64 = (size_t)(l * 4 + ((t - 1) & 3)) * B_ * 128;
            for (int i = tid; i < nb * 128; i += 512) {
                const int bb = i >> 7, up = i & 127;
                unsigned long long v = __hip_atomic_load(
                    hx64 + base64 + (size_t)(b0 + bb) * 128 + up, __ATOMIC_RELAXED, AG);
                *(float2*)&sH[bb * 512 + 256 + up * 2] =
                    make_float2(__uint_as_float((unsigned)v),
                                __uint_as_float((unsigned)(v >> 32)));
            }
        }
        __syncthreads();

        // ---- compute: per batch, 128-FMA dot of W row-quarter with sH ----
        for (int bb = 0; bb < nb; ++bb) {
            const float4* hp = sH4 + bb * 128 + kq * 32;
            float a0 = 0.f, a1 = 0.f, a2 = 0.f, a3 = 0.f;
            #pragma unroll
            for (int i = 0; i < 32; i += 4) {
                float4 w0 = wreg[i + 0], h0 = hp[i + 0];
                float4 w1 = wreg[i + 1], h1 = hp[i + 1];
                float4 w2 = wreg[i + 2], h2 = hp[i + 2];
                float4 w3 = wreg[i + 3], h3 = hp[i + 3];
                a0 += w0.x * h0.x + w0.y * h0.y + w0.z * h0.z + w0.w * h0.w;
                a1 += w1.x * h1.x + w1.y * h1.y + w1.z * h1.z + w1.w * h1.w;
                a2 += w2.x * h2.x + w2.y * h2.y + w2.z * h2.z + w2.w * h2.w;
                a3 += w3.x * h3.x + w3.y * h3.y + w3.z * h3.z + w3.w * h3.w;
            }
            float acc = (a0 + a1) + (a2 + a3);
            acc += __shfl_xor(acc, 16);      // sum kq pairs
            acc += __shfl_xor(acc, 32);      // full K sum
            if (kq == 0) sG[bb * 128 + gr] = acc;
        }
        __syncthreads();

        // ---- pointwise + publish ----
        for (int i = tid; i < nb * 32; i += 512) {
            const int bb = i >> 5, u2 = i & 31;
            const float gi = sG[bb * 128 +       u2] + sB[      u2];
            const float gf = sG[bb * 128 +  32 + u2] + sB[ 32 + u2];
            const float gg = sG[bb * 128 +  64 + u2] + sB[ 64 + u2];
            const float go = sG[bb * 128 +  96 + u2] + sB[ 96 + u2];
            const float I = sigm(gi), F = sigm(gf);
            const float Gt = tanhf(gg), O = sigm(go);
            const float cc = F * cL[i] + I * Gt;
            cL[i] = cc;
            const float h = O * tanhf(cc);
            const int bg = b0 + bb;
            const int unit = s * 32 + u2;
            __hip_atomic_store(hx + ((size_t)(l * 4 + (t & 3)) * B_ + bg) * H_ + unit,
                               h, __ATOMIC_RELAXED, AG);
            if (l == L_ - 1)
                hbuf[((size_t)bg * T_ + t) * H_ + unit] = h;
        }

        asm volatile("s_waitcnt vmcnt(0)" ::: "memory");
        __syncthreads();   // all ring stores drained before flag
        if (tid == 0)
            __hip_atomic_store(flg + (l * NCHK + c) * 32 + s, t + 1, __ATOMIC_RELAXED, AG);
    }
}

// ---- final FC ----
extern "C" __global__ void __launch_bounds__(128)
fc_kernel(const float* __restrict__ hbuf, const float* __restrict__ fcw,
          const float* __restrict__ fcb, float* __restrict__ out) {
    __shared__ float wsm[256];
    const int tid = threadIdx.x;
    const int b = blockIdx.x;
    if (tid < 64) ((float4*)wsm)[tid] = ((const float4*)fcw)[tid];
    __syncthreads();
    if (tid < T_) {
        const float4* h4p = (const float4*)(hbuf + ((size_t)b * T_ + tid) * H_);
        const float4* w4p = (const float4*)wsm;
        float acc = fcb[0];
        #pragma unroll 8
        for (int k4 = 0; k4 < 64; ++k4) {
            float4 h4 = h4p[k4], w4 = w4p[k4];
            acc += h4.x * w4.x + h4.y * w4.y + h4.z * w4.z + h4.w * w4.w;
        }
        out[b * T_ + tid] = acc;
    }
}

extern "C" void kernel_launch(void* const* d_in, const int* in_sizes, int n_in,
                              void* d_out, int out_size, void* d_ws, size_t ws_size,
                              hipStream_t stream) {
    (void)in_sizes; (void)n_in; (void)out_size; (void)ws_size;
    const float* x    = (const float*)d_in[0];
    const float* Wih0 = (const float*)d_in[1];
    const float* Wihr = (const float*)d_in[2];
    const float* Whh  = (const float*)d_in[3];
    const float* bih  = (const float*)d_in[4];
    const float* bhh  = (const float*)d_in[5];
    const float* fcw  = (const float*)d_in[6];
    const float* fcb  = (const float*)d_in[7];
    float* out = (float*)d_out;
    float* ws  = (float*)d_ws;

    float* hbuf = ws;
    float* hx   = ws + HBUF_FLOATS;
    int*   flg  = (int*)(ws + HBUF_FLOATS + HX_FLOATS);

    hipMemsetAsync(flg, 0, FLG_INTS * sizeof(int), stream);
    hipLaunchKernelGGL(wave_kernel, dim3(L_ * NCHK * NSL), dim3(512),
                       SMEM_FLOATS * sizeof(float), stream,
                       x, Wih0, Wihr, Whh, bih, bhh, hbuf, hx, flg);
    hipLaunchKernelGGL(fc_kernel, dim3(B_), dim3(128), 0, stream, hbuf, fcw, fcb, out);
}

// Round 13
// 3854.348 us; speedup vs baseline: 1.0721x; 1.0721x over previous
//
#include <hip/hip_runtime.h>

#define B_ 256
#define T_ 80
#define IN_ 39
#define H_ 256
#define G_ 1024
#define L_ 5
#define NCHK 6          // batch chunks per layer
#define NSL 8           // unit slices per layer (32 units x 4 gates each)

#define HBUF_FLOATS (B_ * T_ * H_)        // 5,242,880 (20 MB)
#define HX_FLOATS   (L_ * 4 * B_ * H_)    // 1,310,720 (5 MB): ring hx[l][slot][b][u]
#define FLG_INTS    (L_ * NCHK * 32)      // one 128B line per (l,c); words 0..7 = slices

// LDS plan (dynamic, floats). sH padded: per-batch stride 528, K-quarter
// stride 132 (33 float4) -> the 4 kq thread-groups hit distinct bank quads.
#define SH_STRIDE 528
#define Q_STRIDE  132
#define SH_OFF 0
#define SG_OFF (43 * SH_STRIDE)                  // 22704
#define CL_OFF (SG_OFF + 43 * 128)               // 28208
#define SB_OFF (CL_OFF + 43 * 32)                // 29584
#define SMEM_FLOATS (SB_OFF + 128)               // 29712 floats = 118,848 B

#define AG __HIP_MEMORY_SCOPE_AGENT

__device__ __forceinline__ float sigm(float x) { return 1.0f / (1.0f + expf(-x)); }

// ---- wavefront kernel: 240 blocks = 5 layers x 6 chunks x 8 slices ----
// Same proven structure/sync as round 11 (passed, absmax 3.8e-6): MALL ring
// hx[l][4 slots] + per-slice flag stores; polls: intra (l,c) >= t, inter
// (l-1,c) >= t+1, ring-gate (l+1,c) >= t-3. DAG via potential 5t+l; all 240
// blocks co-resident (1 block/CU). Fixed here: LDS bank-conflict padding and
// register-pinned W fragments (prevent compiler remat from L2).
extern "C" __global__ void __launch_bounds__(512, 2)
wave_kernel(const float* __restrict__ x,
            const float* __restrict__ Wih0, const float* __restrict__ Wihr,
            const float* __restrict__ Whh,
            const float* __restrict__ bih, const float* __restrict__ bhh,
            float* __restrict__ hbuf, float* __restrict__ hx,
            int* __restrict__ flg)
{
    extern __shared__ float smem[];
    float* sH = smem + SH_OFF;   // [nb][528] : 4 padded quarters of [h_in|h_prev]
    float* sG = smem + SG_OFF;   // [nb][128] : reduced gate pre-activations
    float* cL = smem + CL_OFF;   // [nb][32]  : cell state (persists across t)
    float* sB = smem + SB_OFF;   // [128]     : bias for this slice

    const int tid = threadIdx.x;
    const int bid = blockIdx.x;
    const int l = bid / (NCHK * NSL);
    const int r = bid % (NCHK * NSL);
    const int c = r >> 3;
    const int s = r & 7;

    const int b0 = (c * B_) / NCHK;
    const int b1 = ((c + 1) * B_) / NCHK;
    const int nb = b1 - b0;                  // 42 or 43

    const int wv = tid >> 6;
    const int lane = tid & 63;
    const int kq = (lane >> 4) & 3;          // K-quarter: 0,1=input side; 2,3=recurrent
    const int gr = wv * 16 + (lane & 15);    // gate-row 0..127 within slice
    const int g  = gr >> 5, uu = gr & 31;
    const int grow = g * 256 + s * 32 + uu;  // global gate row in [0,1024)

    // ---- W fragment into registers: 128 consecutive K entries of row grow ----
    float4 wreg[32];
    if (kq >= 2) {
        const float* wsrc = Whh + ((size_t)l * G_ + grow) * H_ + (size_t)(kq - 2) * 128;
        #pragma unroll
        for (int i = 0; i < 32; ++i) wreg[i] = *(const float4*)(wsrc + i * 4);
    } else if (l == 0) {
        const float* wsrc = Wih0 + (size_t)grow * IN_;
        #pragma unroll
        for (int i = 0; i < 32; ++i) {
            float v0 = 0.f, v1 = 0.f, v2 = 0.f, v3 = 0.f;
            const int k = kq * 128 + i * 4;
            if (k + 0 < IN_) v0 = wsrc[k + 0];
            if (k + 1 < IN_) v1 = wsrc[k + 1];
            if (k + 2 < IN_) v2 = wsrc[k + 2];
            if (k + 3 < IN_) v3 = wsrc[k + 3];
            wreg[i] = make_float4(v0, v1, v2, v3);
        }
    } else {
        const float* wsrc = Wihr + (size_t)(l - 1) * G_ * H_
                          + (size_t)grow * H_ + (size_t)kq * 128;
        #pragma unroll
        for (int i = 0; i < 32; ++i) wreg[i] = *(const float4*)(wsrc + i * 4);
    }
    // Pin W in VGPRs: values become asm-defined -> compiler cannot
    // rematerialize the global loads inside the batch loop (r11's 55us bug).
    #pragma unroll
    for (int i = 0; i < 32; ++i)
        asm volatile("" : "+v"(wreg[i].x), "+v"(wreg[i].y),
                          "+v"(wreg[i].z), "+v"(wreg[i].w));

    if (tid < 128)
        sB[tid] = bih[l * G_ + (tid >> 5) * 256 + s * 32 + (tid & 31)]
                + bhh[l * G_ + (tid >> 5) * 256 + s * 32 + (tid & 31)];
    for (int i = tid; i < nb * 32; i += 512) cL[i] = 0.0f;

    const unsigned long long* hx64 = (const unsigned long long*)hx;

    for (int t = 0; t < T_; ++t) {
        // ---- polls (24 scout threads; flag value = published step + 1) ----
        if (tid < 24) {
            const int which = tid >> 3, sp = tid & 7;
            const int* fp = nullptr; int tgt = 0;
            if (which == 0) {
                if (t > 0) { fp = flg + (l * NCHK + c) * 32 + sp; tgt = t; }
            } else if (which == 1) {
                if (l > 0) { fp = flg + ((l - 1) * NCHK + c) * 32 + sp; tgt = t + 1; }
            } else {
                if (l < L_ - 1 && t >= 4) { fp = flg + ((l + 1) * NCHK + c) * 32 + sp; tgt = t - 3; }
            }
            if (fp) {
                while (__hip_atomic_load(fp, __ATOMIC_RELAXED, AG) < tgt)
                    __builtin_amdgcn_s_sleep(1);
            }
        }
        __syncthreads();

        // ---- gather h_in (K 0..255 -> quarters 0,1) ----
        if (l == 0) {
            for (int i = tid; i < nb * 256; i += 512) {
                const int bb = i >> 8, u = i & 255;
                sH[bb * SH_STRIDE + (u >> 7) * Q_STRIDE + (u & 127)] =
                    (u < IN_) ? x[((size_t)(b0 + bb) * T_ + t) * IN_ + u] : 0.0f;
            }
        } else {
            const size_t base64 = (size_t)((l - 1) * 4 + (t & 3)) * B_ * 128;
            for (int i = tid; i < nb * 128; i += 512) {
                const int bb = i >> 7, up = i & 127;
                unsigned long long v = __hip_atomic_load(
                    hx64 + base64 + (size_t)(b0 + bb) * 128 + up, __ATOMIC_RELAXED, AG);
                const int k = up * 2;
                *(float2*)&sH[bb * SH_STRIDE + (k >> 7) * Q_STRIDE + (k & 127)] =
                    make_float2(__uint_as_float((unsigned)v),
                                __uint_as_float((unsigned)(v >> 32)));
            }
        }
        // ---- gather h_prev (K 256..511 -> quarters 2,3) ----
        if (t == 0) {
            for (int i = tid; i < nb * 256; i += 512) {
                const int bb = i >> 8, u = i & 255;
                sH[bb * SH_STRIDE + 2 * Q_STRIDE + (u >> 7) * Q_STRIDE + (u & 127)] = 0.0f;
            }
        } else {
            const size_t base64 = (size_t)(l * 4 + ((t - 1) & 3)) * B_ * 128;
            for (int i = tid; i < nb * 128; i += 512) {
                const int bb = i >> 7, up = i & 127;
                unsigned long long v = __hip_atomic_load(
                    hx64 + base64 + (size_t)(b0 + bb) * 128 + up, __ATOMIC_RELAXED, AG);
                const int k = up * 2;
                *(float2*)&sH[bb * SH_STRIDE + 2 * Q_STRIDE + (k >> 7) * Q_STRIDE + (k & 127)] =
                    make_float2(__uint_as_float((unsigned)v),
                                __uint_as_float((unsigned)(v >> 32)));
            }
        }
        __syncthreads();

        // ---- compute: per batch, 128-FMA dot of W row-quarter with sH ----
        for (int bb = 0; bb < nb; ++bb) {
            const float4* hp = (const float4*)(sH + bb * SH_STRIDE + kq * Q_STRIDE);
            float a0 = 0.f, a1 = 0.f, a2 = 0.f, a3 = 0.f;
            #pragma unroll
            for (int i = 0; i < 32; i += 4) {
                float4 w0 = wreg[i + 0], h0 = hp[i + 0];
                float4 w1 = wreg[i + 1], h1 = hp[i + 1];
                float4 w2 = wreg[i + 2], h2 = hp[i + 2];
                float4 w3 = wreg[i + 3], h3 = hp[i + 3];
                a0 += w0.x * h0.x + w0.y * h0.y + w0.z * h0.z + w0.w * h0.w;
                a1 += w1.x * h1.x + w1.y * h1.y + w1.z * h1.z + w1.w * h1.w;
                a2 += w2.x * h2.x + w2.y * h2.y + w2.z * h2.z + w2.w * h2.w;
                a3 += w3.x * h3.x + w3.y * h3.y + w3.z * h3.z + w3.w * h3.w;
            }
            float acc = (a0 + a1) + (a2 + a3);
            acc += __shfl_xor(acc, 16);      // sum kq pairs (0+1, 2+3)
            acc += __shfl_xor(acc, 32);      // full K sum
            if (kq == 0) sG[bb * 128 + gr] = acc;
        }
        __syncthreads();

        // ---- pointwise + publish ----
        for (int i = tid; i < nb * 32; i += 512) {
            const int bb = i >> 5, u2 = i & 31;
            const float gi = sG[bb * 128 +       u2] + sB[      u2];
            const float gf = sG[bb * 128 +  32 + u2] + sB[ 32 + u2];
            const float gg = sG[bb * 128 +  64 + u2] + sB[ 64 + u2];
            const float go = sG[bb * 128 +  96 + u2] + sB[ 96 + u2];
            const float I = sigm(gi), F = sigm(gf);
            const float Gt = tanhf(gg), O = sigm(go);
            const float cc = F * cL[i] + I * Gt;
            cL[i] = cc;
            const float h = O * tanhf(cc);
            const int bg = b0 + bb;
            const int unit = s * 32 + u2;
            __hip_atomic_store(hx + ((size_t)(l * 4 + (t & 3)) * B_ + bg) * H_ + unit,
                               h, __ATOMIC_RELAXED, AG);
            if (l == L_ - 1)
                hbuf[((size_t)bg * T_ + t) * H_ + unit] = h;
        }

        asm volatile("s_waitcnt vmcnt(0)" ::: "memory");
        __syncthreads();   // all ring stores drained before flag
        if (tid == 0)
            __hip_atomic_store(flg + (l * NCHK + c) * 32 + s, t + 1, __ATOMIC_RELAXED, AG);
    }
}

// ---- final FC ----
extern "C" __global__ void __launch_bounds__(128)
fc_kernel(const float* __restrict__ hbuf, const float* __restrict__ fcw,
          const float* __restrict__ fcb, float* __restrict__ out) {
    __shared__ float wsm[256];
    const int tid = threadIdx.x;
    const int b = blockIdx.x;
    if (tid < 64) ((float4*)wsm)[tid] = ((const float4*)fcw)[tid];
    __syncthreads();
    if (tid < T_) {
        const float4* h4p = (const float4*)(hbuf + ((size_t)b * T_ + tid) * H_);
        const float4* w4p = (const float4*)wsm;
        float acc = fcb[0];
        #pragma unroll 8
        for (int k4 = 0; k4 < 64; ++k4) {
            float4 h4 = h4p[k4], w4 = w4p[k4];
            acc += h4.x * w4.x + h4.y * w4.y + h4.z * w4.z + h4.w * w4.w;
        }
        out[b * T_ + tid] = acc;
    }
}

extern "C" void kernel_launch(void* const* d_in, const int* in_sizes, int n_in,
                              void* d_out, int out_size, void* d_ws, size_t ws_size,
                              hipStream_t stream) {
    (void)in_sizes; (void)n_in; (void)out_size; (void)ws_size;
    const float* x    = (const float*)d_in[0];
    const float* Wih0 = (const float*)d_in[1];
    const float* Wihr = (const float*)d_in[2];
    const float* Whh  = (const float*)d_in[3];
    const float* bih  = (const float*)d_in[4];
    const float* bhh  = (const float*)d_in[5];
    const float* fcw  = (const float*)d_in[6];
    const float* fcb  = (const float*)d_in[7];
    float* out = (float*)d_out;
    float* ws  = (float*)d_ws;

    float* hbuf = ws;
    float* hx   = ws + HBUF_FLOATS;
    int*   flg  = (int*)(ws + HBUF_FLOATS + HX_FLOATS);

    hipMemsetAsync(flg, 0, FLG_INTS * sizeof(int), stream);
    hipLaunchKernelGGL(wave_kernel, dim3(L_ * NCHK * NSL), dim3(512),
                       SMEM_FLOATS * sizeof(float), stream,
                       x, Wih0, Wihr, Whh, bih, bhh, hbuf, hx, flg);
    hipLaunchKernelGGL(fc_kernel, dim3(B_), dim3(128), 0, stream, hbuf, fcw, fcb, out);
}

// Round 14
// 2947.468 us; speedup vs baseline: 1.4019x; 1.3077x over previous
//
#include <hip/hip_runtime.h>

#define B_ 256
#define T_ 80
#define IN_ 39
#define H_ 256
#define G_ 1024
#define L_ 5
#define TC_ 16
#define NCH_ 5

#define XP_FLOATS   (B_ * TC_ * G_)     // 4,194,304
#define HBUF_FLOATS (B_ * T_ * H_)      // 5,242,880
#define CBUF_FLOATS (B_ * H_)           // 65,536
#define WG_FLOATS   (L_ * G_ * H_)      // 1,310,720
#define HX_FLOATS   (2 * 32 * 2048)     // 131,072
#define FLG_OFF_FLOATS (XP_FLOATS + HBUF_FLOATS + CBUF_FLOATS + WG_FLOATS + HX_FLOATS)

#define AG __HIP_MEMORY_SCOPE_AGENT

__device__ __forceinline__ float sigm(float x) { return 1.0f / (1.0f + expf(-x)); }
__device__ __forceinline__ void fma4(float4& a, float s, const float4& w) {
    a.x = fmaf(s, w.x, a.x); a.y = fmaf(s, w.y, a.y);
    a.z = fmaf(s, w.z, a.z); a.w = fmaf(s, w.w, a.w);
}
__device__ __forceinline__ void red4(float4& a) {
    a.x += __shfl_xor(a.x, 32); a.y += __shfl_xor(a.y, 32);
    a.z += __shfl_xor(a.z, 32); a.w += __shfl_xor(a.w, 32);
}

// MALL-coherent 32B load: sc0+sc1 = the cache-op bits the compiler emits for
// agent-scope atomic loads (bypass L1+L2 to the coherence point), but 16B wide.
__device__ __forceinline__ void ld_mall_32B(const float* p, float4& a, float4& b) {
    asm volatile("global_load_dwordx4 %0, %2, off sc0 sc1\n\t"
                 "global_load_dwordx4 %1, %2, off offset:16 sc0 sc1\n\t"
                 "s_waitcnt vmcnt(0)"
                 : "=&v"(a), "=&v"(b) : "v"(p) : "memory");
}

// ---- Wg: per-slice interleaved W_hh: Wg[l][s][k][j][g] = Whh[l][g*256+s*32+j][k] ----
extern "C" __global__ void __launch_bounds__(256)
wt_kernel(const float* __restrict__ Whh, float* __restrict__ Wg) {
    const int gid = blockIdx.x * 256 + threadIdx.x;
    const int g4 = gid & 3;
    const int j  = (gid >> 2) & 31;
    const int k  = (gid >> 7) & 255;
    const int s  = (gid >> 15) & 7;
    const int l  = gid >> 18;
    Wg[gid] = Whh[((size_t)(l * 1024 + g4 * 256 + s * 32 + j)) * 256 + k];
}

// ---- projection GEMM; xp is GATE-PACKED: xp[row][unit][gate] ----
extern "C" __global__ void __launch_bounds__(256)
proj_kernel(const float* __restrict__ src, const float* __restrict__ Wih,
            const float* __restrict__ bihl, const float* __restrict__ bhhl,
            float* __restrict__ xp, int K, int t0) {
    __shared__ float As[16 * 68];
    __shared__ float Bs[16 * 68];
    const int tid = threadIdx.x;
    const int mt = blockIdx.x >> 4, nt = blockIdx.x & 15;
    const int tx = tid & 15, ty = tid >> 4;
    const int lr = tid >> 2, lc4 = (tid & 3) << 2;

    const int ar = mt * 64 + lr;
    const int ab = ar >> 4;
    const int at = t0 + (ar & 15);
    const float* arow = src + ((size_t)ab * T_ + at) * K;
    const float* brow = Wih + (size_t)(nt * 64 + lr) * K;

    float acc[4][4];
    #pragma unroll
    for (int i = 0; i < 4; ++i)
        #pragma unroll
        for (int j = 0; j < 4; ++j) acc[i][j] = 0.0f;

    for (int k0 = 0; k0 < K; k0 += 16) {
        __syncthreads();
        if (K == IN_) {
            #pragma unroll
            for (int i = 0; i < 4; ++i) {
                int k = k0 + lc4 + i;
                As[(lc4 + i) * 68 + lr] = (k < IN_) ? arow[k] : 0.0f;
                Bs[(lc4 + i) * 68 + lr] = (k < IN_) ? brow[k] : 0.0f;
            }
        } else {
            float4 av = *(const float4*)(arow + k0 + lc4);
            float4 bv = *(const float4*)(brow + k0 + lc4);
            As[(lc4 + 0) * 68 + lr] = av.x;
            As[(lc4 + 1) * 68 + lr] = av.y;
            As[(lc4 + 2) * 68 + lr] = av.z;
            As[(lc4 + 3) * 68 + lr] = av.w;
            Bs[(lc4 + 0) * 68 + lr] = bv.x;
            Bs[(lc4 + 1) * 68 + lr] = bv.y;
            Bs[(lc4 + 2) * 68 + lr] = bv.z;
            Bs[(lc4 + 3) * 68 + lr] = bv.w;
        }
        __syncthreads();
        #pragma unroll
        for (int kk = 0; kk < 16; ++kk) {
            float4 a4 = *(const float4*)&As[kk * 68 + ty * 4];
            float4 b4 = *(const float4*)&Bs[kk * 68 + tx * 4];
            acc[0][0] += a4.x * b4.x; acc[0][1] += a4.x * b4.y;
            acc[0][2] += a4.x * b4.z; acc[0][3] += a4.x * b4.w;
            acc[1][0] += a4.y * b4.x; acc[1][1] += a4.y * b4.y;
            acc[1][2] += a4.y * b4.z; acc[1][3] += a4.y * b4.w;
            acc[2][0] += a4.z * b4.x; acc[2][1] += a4.z * b4.y;
            acc[2][2] += a4.z * b4.z; acc[2][3] += a4.z * b4.w;
            acc[3][0] += a4.w * b4.x; acc[3][1] += a4.w * b4.y;
            acc[3][2] += a4.w * b4.z; acc[3][3] += a4.w * b4.w;
        }
    }
    const int col = nt * 64 + tx * 4;          // old linear gate-col
    const int g  = col >> 8;                   // gate 0..3
    const int u0 = col & 255;                  // unit base (4 consecutive units)
    const float bs0 = bihl[col + 0] + bhhl[col + 0];
    const float bs1 = bihl[col + 1] + bhhl[col + 1];
    const float bs2 = bihl[col + 2] + bhhl[col + 2];
    const float bs3 = bihl[col + 3] + bhhl[col + 3];
    #pragma unroll
    for (int i = 0; i < 4; ++i) {
        const int row = mt * 64 + ty * 4 + i;
        float* xr = xp + (size_t)row * G_;
        xr[(u0 + 0) * 4 + g] = acc[i][0] + bs0;
        xr[(u0 + 1) * 4 + g] = acc[i][1] + bs1;
        xr[(u0 + 2) * 4 + g] = acc[i][2] + bs2;
        xr[(u0 + 3) * 4 + g] = acc[i][3] + bs3;
    }
}

// ---- recurrence: r9 verbatim except (1) hx gather via 16B sc0+sc1 loads
// (half the MALL transactions of u64 atomics), (2) xp read as one coalesced
// float4 (gate-packed layout). Publish/flag/poll scheme unchanged (proven).
extern "C" __global__ void __launch_bounds__(512, 2)
rec7_kernel(const float* __restrict__ xp, const float* __restrict__ Wg_l,
            float* __restrict__ hbuf, float* __restrict__ cbuf,
            float* __restrict__ hx, int* __restrict__ flg,
            int t0, int chkb, int first) {
    __shared__ float sH[2048];          // hT[k][bb]  (8 KB)
    __shared__ float sP[8 * 32 * 36];   // part[w][jj][36] (36 KB)

    const int tid = threadIdx.x;
    const int bid = blockIdx.x;
    const int grp = bid & 31;
    const int s   = bid >> 5;
    const int jj  = tid & 31;       // main identity: unit
    const int ks  = tid >> 5;       // main identity: k-slice (0..15)
    const int w   = tid >> 6;       // wave id (0..7)
    const int fb  = (tid >> 5) & 7; // finish identity: batch (tid<256)
    const int fj  = tid & 31;       // finish identity: unit
    const int bglob = grp * 8 + fb;
    const int unit  = s * 32 + fj;
    int* flg_g = flg + grp * 32;    // group's 128B line; words 0..7 = slices

    // W fragment into registers: wreg[kk] = 4 gates of unit jj at k = ks*16+kk
    const float4* Wg4 = (const float4*)Wg_l + (size_t)s * 8192;
    float4 wreg[16];
    #pragma unroll
    for (int kk = 0; kk < 16; ++kk)
        wreg[kk] = Wg4[(size_t)(ks * 16 + kk) * 32 + jj];

    float creg = 0.0f;
    if (tid < 256 && !first) creg = cbuf[(size_t)bglob * H_ + unit];

    const float4* sH4 = (const float4*)sH;

    for (int tt = 0; tt < TC_; ++tt) {
        const int t = t0 + tt;

        // xp prefetch FIRST: one coalesced float4 (gate-packed layout)
        float x0 = 0.f, x1 = 0.f, x2 = 0.f, x3 = 0.f;
        if (tid < 256) {
            const float4 xv = *(const float4*)&xp[((size_t)bglob * TC_ + tt) * G_ + unit * 4];
            x0 = xv.x; x1 = xv.y; x2 = xv.z; x3 = xv.w;
        }

        // ---- phase A: gather h(t-1) into sH (hT[k][bb]) ----
        if (tt == 0) {
            if (first) {
                for (int i = tid; i < 2048; i += 512) sH[i] = 0.0f;
            } else if (tid < 256) {
                const int u = tid;
                #pragma unroll
                for (int bb = 0; bb < 8; ++bb)
                    sH[u * 8 + bb] = hbuf[((size_t)(grp * 8 + bb) * T_ + (t0 - 1)) * H_ + u];
            }
        } else {
            if (tid < 8) {                  // scouts: one flag per slice
                const int tgt = chkb + tt;
                while (__hip_atomic_load(flg_g + tid, __ATOMIC_RELAXED, AG) < tgt)
                    __builtin_amdgcn_s_sleep(1);
            }
            __syncthreads();
            if (tid < 256) {
                const float* hsf = hx + (size_t)(((tt - 1) & 1) * 32 + grp) * 2048
                                      + (size_t)tid * 8;
                float4 fa, fbv;
                ld_mall_32B(hsf, fa, fbv);
                *(float4*)&sH[tid * 8] = fa;
                *(float4*)&sH[tid * 8 + 4] = fbv;
            }
        }

        __syncthreads();  // (b) sH ready

        // ---- phase B: k-loop, W from registers, h broadcast from LDS ----
        float4 a0 = {0,0,0,0}, a1 = {0,0,0,0}, a2 = {0,0,0,0}, a3 = {0,0,0,0};
        float4 a4 = {0,0,0,0}, a5 = {0,0,0,0}, a6 = {0,0,0,0}, a7 = {0,0,0,0};
        #pragma unroll
        for (int kk = 0; kk < 16; ++kk) {
            const int k = ks * 16 + kk;
            const float4 wv = wreg[kk];
            const float4 ha = sH4[k * 2];
            const float4 hb = sH4[k * 2 + 1];
            fma4(a0, ha.x, wv); fma4(a1, ha.y, wv);
            fma4(a2, ha.z, wv); fma4(a3, ha.w, wv);
            fma4(a4, hb.x, wv); fma4(a5, hb.y, wv);
            fma4(a6, hb.z, wv); fma4(a7, hb.w, wv);
        }
        red4(a0); red4(a1); red4(a2); red4(a3);
        red4(a4); red4(a5); red4(a6); red4(a7);
        if ((tid & 63) < 32) {
            float4* pp = (float4*)&sP[(w * 32 + jj) * 36];
            pp[0] = a0; pp[1] = a1; pp[2] = a2; pp[3] = a3;
            pp[4] = a4; pp[5] = a5; pp[6] = a6; pp[7] = a7;
        }
        __syncthreads();  // (c) partials ready

        // ---- phase C: finish (tid < 256) ----
        if (tid < 256) {
            float4 g4;
            g4.x = x0; g4.y = x1; g4.z = x2; g4.w = x3;
            #pragma unroll
            for (int w2 = 0; w2 < 8; ++w2) {
                const float4 pw = *(const float4*)&sP[(w2 * 32 + fj) * 36 + fb * 4];
                g4.x += pw.x; g4.y += pw.y; g4.z += pw.z; g4.w += pw.w;
            }
            const float I = sigm(g4.x);
            const float F = sigm(g4.y);
            const float Gt = tanhf(g4.z);
            const float O = sigm(g4.w);
            creg = F * creg + I * Gt;
            const float hval = O * tanhf(creg);
            hbuf[((size_t)bglob * T_ + t) * H_ + unit] = hval;

            if (tt < TC_ - 1) {
                __hip_atomic_store(hx + (size_t)((tt & 1) * 32 + grp) * 2048 + unit * 8 + fb,
                                   hval, __ATOMIC_RELAXED, AG);
            }
        }

        if (tt < TC_ - 1) {
            asm volatile("s_waitcnt vmcnt(0)" ::: "memory");
            __syncthreads();  // (d) all publishes drained
            if (tid == 0)
                __hip_atomic_store(flg_g + s, chkb + tt + 1, __ATOMIC_RELAXED, AG);
        }
    }

    if (tid < 256) cbuf[(size_t)bglob * H_ + unit] = creg;
}

// ---- final FC ----
extern "C" __global__ void __launch_bounds__(128)
fc_kernel(const float* __restrict__ hbuf, const float* __restrict__ fcw,
          const float* __restrict__ fcb, float* __restrict__ out) {
    __shared__ float wsm[256];
    const int tid = threadIdx.x;
    const int b = blockIdx.x;
    if (tid < 64) ((float4*)wsm)[tid] = ((const float4*)fcw)[tid];
    __syncthreads();
    if (tid < T_) {
        const float4* h4p = (const float4*)(hbuf + ((size_t)b * T_ + tid) * H_);
        const float4* w4p = (const float4*)wsm;
        float acc = fcb[0];
        #pragma unroll 8
        for (int k4 = 0; k4 < 64; ++k4) {
            float4 h4 = h4p[k4], w4 = w4p[k4];
            acc += h4.x * w4.x + h4.y * w4.y + h4.z * w4.z + h4.w * w4.w;
        }
        out[b * T_ + tid] = acc;
    }
}

extern "C" void kernel_launch(void* const* d_in, const int* in_sizes, int n_in,
                              void* d_out, int out_size, void* d_ws, size_t ws_size,
                              hipStream_t stream) {
    (void)in_sizes; (void)n_in; (void)out_size; (void)ws_size;
    const float* x    = (const float*)d_in[0];
    const float* Wih0 = (const float*)d_in[1];
    const float* Wihr = (const float*)d_in[2];
    const float* Whh  = (const float*)d_in[3];
    const float* bih  = (const float*)d_in[4];
    const float* bhh  = (const float*)d_in[5];
    const float* fcw  = (const float*)d_in[6];
    const float* fcb  = (const float*)d_in[7];
    float* out = (float*)d_out;
    float* ws  = (float*)d_ws;

    float* xp   = ws;
    float* hbuf = ws + XP_FLOATS;
    float* cbuf = hbuf + HBUF_FLOATS;
    float* wg   = cbuf + CBUF_FLOATS;
    float* hx   = wg + WG_FLOATS;
    int*   flg  = (int*)(ws + FLG_OFF_FLOATS);

    hipMemsetAsync(flg, 0, 32 * 32 * sizeof(int), stream);
    hipLaunchKernelGGL(wt_kernel, dim3(WG_FLOATS / 256), dim3(256), 0, stream, Whh, wg);

    for (int l = 0; l < L_; ++l) {
        const int K = (l == 0) ? IN_ : H_;
        const float* src = (l == 0) ? x : hbuf;
        const float* Wih = (l == 0) ? Wih0 : (Wihr + (size_t)(l - 1) * G_ * H_);
        const float* Wg_l = wg + (size_t)l * (G_ * H_);
        for (int ch = 0; ch < NCH_; ++ch) {
            const int t0 = ch * TC_;
            const int chkb = (l * NCH_ + ch) * (TC_ - 1);
            hipLaunchKernelGGL(proj_kernel, dim3(1024), dim3(256), 0, stream,
                               src, Wih, bih + l * G_, bhh + l * G_, xp, K, t0);
            hipLaunchKernelGGL(rec7_kernel, dim3(256), dim3(512), 0, stream,
                               xp, Wg_l, hbuf, cbuf, hx, flg, t0, chkb, ch == 0 ? 1 : 0);
        }
    }
    hipLaunchKernelGGL(fc_kernel, dim3(B_), dim3(128), 0, stream, hbuf, fcw, fcb, out);
}

// Round 15
// 2540.550 us; speedup vs baseline: 1.6265x; 1.1602x over previous
//
#include <hip/hip_runtime.h>

#define B_ 256
#define T_ 80
#define IN_ 39
#define H_ 256
#define G_ 1024
#define L_ 5
#define TC_ 16
#define NCH_ 5

#define XP_FLOATS   (B_ * TC_ * G_)     // 4,194,304
#define HBUF_FLOATS (B_ * T_ * H_)      // 5,242,880
#define CBUF_FLOATS (B_ * H_)           // 65,536
#define WG_FLOATS   (L_ * G_ * H_)      // 1,310,720
#define HX_FLOATS   (2 * 32 * 2048)     // 131,072
#define FLG_OFF_FLOATS (XP_FLOATS + HBUF_FLOATS + CBUF_FLOATS + WG_FLOATS + HX_FLOATS)

#define AG __HIP_MEMORY_SCOPE_AGENT

__device__ __forceinline__ float sigm(float x) { return 1.0f / (1.0f + expf(-x)); }
__device__ __forceinline__ void fma4(float4& a, float s, const float4& w) {
    a.x = fmaf(s, w.x, a.x); a.y = fmaf(s, w.y, a.y);
    a.z = fmaf(s, w.z, a.z); a.w = fmaf(s, w.w, a.w);
}
__device__ __forceinline__ void red4(float4& a) {
    a.x += __shfl_xor(a.x, 32); a.y += __shfl_xor(a.y, 32);
    a.z += __shfl_xor(a.z, 32); a.w += __shfl_xor(a.w, 32);
}

// MALL-coherent 32B load (sc0+sc1 like agent-scope atomic loads, 16B wide).
__device__ __forceinline__ void ld_mall_32B(const float* p, float4& a, float4& b) {
    asm volatile("global_load_dwordx4 %0, %2, off sc0 sc1\n\t"
                 "global_load_dwordx4 %1, %2, off offset:16 sc0 sc1\n\t"
                 "s_waitcnt vmcnt(0)"
                 : "=&v"(a), "=&v"(b) : "v"(p) : "memory");
}

// ---- Wg: per-slice interleaved W_hh: Wg[l][s][k][j][g] = Whh[l][g*256+s*32+j][k] ----
extern "C" __global__ void __launch_bounds__(256)
wt_kernel(const float* __restrict__ Whh, float* __restrict__ Wg) {
    const int gid = blockIdx.x * 256 + threadIdx.x;
    const int g4 = gid & 3;
    const int j  = (gid >> 2) & 31;
    const int k  = (gid >> 7) & 255;
    const int s  = (gid >> 15) & 7;
    const int l  = gid >> 18;
    Wg[gid] = Whh[((size_t)(l * 1024 + g4 * 256 + s * 32 + j)) * 256 + k];
}

// ---- projection GEMM; xp GATE-PACKED xp[row][unit][gate], coalesced stores ----
// Logical column c == unit*4+gate; weight row for c is r(c)=(c&3)*256+(c>>2),
// so loader row (lr) = (lr&3)*256 + nt*16 + (lr>>2); bias idx j*256+nt*16+tx.
// Each thread's 4 accs are the 4 gates of one unit -> contiguous float4 store.
extern "C" __global__ void __launch_bounds__(256)
proj_kernel(const float* __restrict__ src, const float* __restrict__ Wih,
            const float* __restrict__ bihl, const float* __restrict__ bhhl,
            float* __restrict__ xp, int K, int t0) {
    __shared__ float As[16 * 68];
    __shared__ float Bs[16 * 68];
    const int tid = threadIdx.x;
    const int mt = blockIdx.x >> 4, nt = blockIdx.x & 15;
    const int tx = tid & 15, ty = tid >> 4;
    const int lr = tid >> 2, lc4 = (tid & 3) << 2;

    const int ar = mt * 64 + lr;
    const int ab = ar >> 4;
    const int at = t0 + (ar & 15);
    const float* arow = src + ((size_t)ab * T_ + at) * K;
    const int brow_idx = (lr & 3) * 256 + nt * 16 + (lr >> 2);   // permuted W row
    const float* brow = Wih + (size_t)brow_idx * K;

    float acc[4][4];
    #pragma unroll
    for (int i = 0; i < 4; ++i)
        #pragma unroll
        for (int j = 0; j < 4; ++j) acc[i][j] = 0.0f;

    for (int k0 = 0; k0 < K; k0 += 16) {
        __syncthreads();
        if (K == IN_) {
            #pragma unroll
            for (int i = 0; i < 4; ++i) {
                int k = k0 + lc4 + i;
                As[(lc4 + i) * 68 + lr] = (k < IN_) ? arow[k] : 0.0f;
                Bs[(lc4 + i) * 68 + lr] = (k < IN_) ? brow[k] : 0.0f;
            }
        } else {
            float4 av = *(const float4*)(arow + k0 + lc4);
            float4 bv = *(const float4*)(brow + k0 + lc4);
            As[(lc4 + 0) * 68 + lr] = av.x;
            As[(lc4 + 1) * 68 + lr] = av.y;
            As[(lc4 + 2) * 68 + lr] = av.z;
            As[(lc4 + 3) * 68 + lr] = av.w;
            Bs[(lc4 + 0) * 68 + lr] = bv.x;
            Bs[(lc4 + 1) * 68 + lr] = bv.y;
            Bs[(lc4 + 2) * 68 + lr] = bv.z;
            Bs[(lc4 + 3) * 68 + lr] = bv.w;
        }
        __syncthreads();
        #pragma unroll
        for (int kk = 0; kk < 16; ++kk) {
            float4 a4 = *(const float4*)&As[kk * 68 + ty * 4];
            float4 b4 = *(const float4*)&Bs[kk * 68 + tx * 4];
            acc[0][0] += a4.x * b4.x; acc[0][1] += a4.x * b4.y;
            acc[0][2] += a4.x * b4.z; acc[0][3] += a4.x * b4.w;
            acc[1][0] += a4.y * b4.x; acc[1][1] += a4.y * b4.y;
            acc[1][2] += a4.y * b4.z; acc[1][3] += a4.y * b4.w;
            acc[2][0] += a4.z * b4.x; acc[2][1] += a4.z * b4.y;
            acc[2][2] += a4.z * b4.z; acc[2][3] += a4.z * b4.w;
            acc[3][0] += a4.w * b4.x; acc[3][1] += a4.w * b4.y;
            acc[3][2] += a4.w * b4.z; acc[3][3] += a4.w * b4.w;
        }
    }
    const int unit = nt * 16 + tx;
    const float bs0 = bihl[0 * 256 + unit] + bhhl[0 * 256 + unit];
    const float bs1 = bihl[1 * 256 + unit] + bhhl[1 * 256 + unit];
    const float bs2 = bihl[2 * 256 + unit] + bhhl[2 * 256 + unit];
    const float bs3 = bihl[3 * 256 + unit] + bhhl[3 * 256 + unit];
    #pragma unroll
    for (int i = 0; i < 4; ++i) {
        const int row = mt * 64 + ty * 4 + i;
        float4 o;
        o.x = acc[i][0] + bs0; o.y = acc[i][1] + bs1;
        o.z = acc[i][2] + bs2; o.w = acc[i][3] + bs3;
        *(float4*)&xp[(size_t)row * G_ + unit * 4] = o;   // coalesced, gate-packed
    }
}

// ---- recurrence: r14 rec7 + paired u64 publish (128 stores instead of 256) ----
extern "C" __global__ void __launch_bounds__(512, 2)
rec8_kernel(const float* __restrict__ xp, const float* __restrict__ Wg_l,
            float* __restrict__ hbuf, float* __restrict__ cbuf,
            float* __restrict__ hx, int* __restrict__ flg,
            int t0, int chkb, int first) {
    __shared__ float sH[2048];          // hT[k][bb]  (8 KB)
    __shared__ float sP[8 * 32 * 36];   // part[w][jj][36] (36 KB)

    const int tid = threadIdx.x;
    const int bid = blockIdx.x;
    const int grp = bid & 31;
    const int s   = bid >> 5;
    const int jj  = tid & 31;       // main identity: unit
    const int ks  = tid >> 5;       // main identity: k-slice (0..15)
    const int w   = tid >> 6;       // wave id (0..7)
    const int fb  = (tid >> 5) & 7; // finish identity: batch (tid<256)
    const int fj  = tid & 31;       // finish identity: unit
    const int bglob = grp * 8 + fb;
    const int unit  = s * 32 + fj;
    int* flg_g = flg + grp * 32;    // group's 128B line; words 0..7 = slices

    // W fragment into registers: wreg[kk] = 4 gates of unit jj at k = ks*16+kk
    const float4* Wg4 = (const float4*)Wg_l + (size_t)s * 8192;
    float4 wreg[16];
    #pragma unroll
    for (int kk = 0; kk < 16; ++kk)
        wreg[kk] = Wg4[(size_t)(ks * 16 + kk) * 32 + jj];

    float creg = 0.0f;
    if (tid < 256 && !first) creg = cbuf[(size_t)bglob * H_ + unit];

    const float4* sH4 = (const float4*)sH;

    for (int tt = 0; tt < TC_; ++tt) {
        const int t = t0 + tt;

        // xp prefetch FIRST: one coalesced float4 (gate-packed layout)
        float x0 = 0.f, x1 = 0.f, x2 = 0.f, x3 = 0.f;
        if (tid < 256) {
            const float4 xv = *(const float4*)&xp[((size_t)bglob * TC_ + tt) * G_ + unit * 4];
            x0 = xv.x; x1 = xv.y; x2 = xv.z; x3 = xv.w;
        }

        // ---- phase A: gather h(t-1) into sH (hT[k][bb]) ----
        if (tt == 0) {
            if (first) {
                for (int i = tid; i < 2048; i += 512) sH[i] = 0.0f;
            } else if (tid < 256) {
                const int u = tid;
                #pragma unroll
                for (int bb = 0; bb < 8; ++bb)
                    sH[u * 8 + bb] = hbuf[((size_t)(grp * 8 + bb) * T_ + (t0 - 1)) * H_ + u];
            }
        } else {
            if (tid < 8) {                  // scouts: one flag per slice
                const int tgt = chkb + tt;
                while (__hip_atomic_load(flg_g + tid, __ATOMIC_RELAXED, AG) < tgt)
                    __builtin_amdgcn_s_sleep(1);
            }
            __syncthreads();
            if (tid < 256) {
                const float* hsf = hx + (size_t)(((tt - 1) & 1) * 32 + grp) * 2048
                                      + (size_t)tid * 8;
                float4 fa, fbv;
                ld_mall_32B(hsf, fa, fbv);
                *(float4*)&sH[tid * 8] = fa;
                *(float4*)&sH[tid * 8 + 4] = fbv;
            }
        }

        __syncthreads();  // (b) sH ready

        // ---- phase B: k-loop, W from registers, h broadcast from LDS ----
        float4 a0 = {0,0,0,0}, a1 = {0,0,0,0}, a2 = {0,0,0,0}, a3 = {0,0,0,0};
        float4 a4 = {0,0,0,0}, a5 = {0,0,0,0}, a6 = {0,0,0,0}, a7 = {0,0,0,0};
        #pragma unroll
        for (int kk = 0; kk < 16; ++kk) {
            const int k = ks * 16 + kk;
            const float4 wv = wreg[kk];
            const float4 ha = sH4[k * 2];
            const float4 hb = sH4[k * 2 + 1];
            fma4(a0, ha.x, wv); fma4(a1, ha.y, wv);
            fma4(a2, ha.z, wv); fma4(a3, ha.w, wv);
            fma4(a4, hb.x, wv); fma4(a5, hb.y, wv);
            fma4(a6, hb.z, wv); fma4(a7, hb.w, wv);
        }
        red4(a0); red4(a1); red4(a2); red4(a3);
        red4(a4); red4(a5); red4(a6); red4(a7);
        if ((tid & 63) < 32) {
            float4* pp = (float4*)&sP[(w * 32 + jj) * 36];
            pp[0] = a0; pp[1] = a1; pp[2] = a2; pp[3] = a3;
            pp[4] = a4; pp[5] = a5; pp[6] = a6; pp[7] = a7;
        }
        __syncthreads();  // (c) partials ready

        // ---- phase C: finish (tid < 256) ----
        if (tid < 256) {
            float4 g4;
            g4.x = x0; g4.y = x1; g4.z = x2; g4.w = x3;
            #pragma unroll
            for (int w2 = 0; w2 < 8; ++w2) {
                const float4 pw = *(const float4*)&sP[(w2 * 32 + fj) * 36 + fb * 4];
                g4.x += pw.x; g4.y += pw.y; g4.z += pw.z; g4.w += pw.w;
            }
            const float I = sigm(g4.x);
            const float F = sigm(g4.y);
            const float Gt = tanhf(g4.z);
            const float O = sigm(g4.w);
            creg = F * creg + I * Gt;
            const float hval = O * tanhf(creg);
            hbuf[((size_t)bglob * T_ + t) * H_ + unit] = hval;

            if (tt < TC_ - 1) {
                // paired publish: lanes fb and fb^1 (tid ^ 32) share one u64
                const float hpart = __shfl_xor(hval, 32);
                if ((fb & 1) == 0) {
                    const unsigned long long pv =
                        ((unsigned long long)__float_as_uint(hpart) << 32)
                        | __float_as_uint(hval);
                    unsigned long long* dst = (unsigned long long*)
                        (hx + (size_t)((tt & 1) * 32 + grp) * 2048 + unit * 8 + fb);
                    __hip_atomic_store(dst, pv, __ATOMIC_RELAXED, AG);
                }
            }
        }

        if (tt < TC_ - 1) {
            asm volatile("s_waitcnt vmcnt(0)" ::: "memory");
            __syncthreads();  // (d) all publishes drained
            if (tid == 0)
                __hip_atomic_store(flg_g + s, chkb + tt + 1, __ATOMIC_RELAXED, AG);
        }
    }

    if (tid < 256) cbuf[(size_t)bglob * H_ + unit] = creg;
}

// ---- final FC ----
extern "C" __global__ void __launch_bounds__(128)
fc_kernel(const float* __restrict__ hbuf, const float* __restrict__ fcw,
          const float* __restrict__ fcb, float* __restrict__ out) {
    __shared__ float wsm[256];
    const int tid = threadIdx.x;
    const int b = blockIdx.x;
    if (tid < 64) ((float4*)wsm)[tid] = ((const float4*)fcw)[tid];
    __syncthreads();
    if (tid < T_) {
        const float4* h4p = (const float4*)(hbuf + ((size_t)b * T_ + tid) * H_);
        const float4* w4p = (const float4*)wsm;
        float acc = fcb[0];
        #pragma unroll 8
        for (int k4 = 0; k4 < 64; ++k4) {
            float4 h4 = h4p[k4], w4 = w4p[k4];
            acc += h4.x * w4.x + h4.y * w4.y + h4.z * w4.z + h4.w * w4.w;
        }
        out[b * T_ + tid] = acc;
    }
}

extern "C" void kernel_launch(void* const* d_in, const int* in_sizes, int n_in,
                              void* d_out, int out_size, void* d_ws, size_t ws_size,
                              hipStream_t stream) {
    (void)in_sizes; (void)n_in; (void)out_size; (void)ws_size;
    const float* x    = (const float*)d_in[0];
    const float* Wih0 = (const float*)d_in[1];
    const float* Wihr = (const float*)d_in[2];
    const float* Whh  = (const float*)d_in[3];
    const float* bih  = (const float*)d_in[4];
    const float* bhh  = (const float*)d_in[5];
    const float* fcw  = (const float*)d_in[6];
    const float* fcb  = (const float*)d_in[7];
    float* out = (float*)d_out;
    float* ws  = (float*)d_ws;

    float* xp   = ws;
    float* hbuf = ws + XP_FLOATS;
    float* cbuf = hbuf + HBUF_FLOATS;
    float* wg   = cbuf + CBUF_FLOATS;
    float* hx   = wg + WG_FLOATS;
    int*   flg  = (int*)(ws + FLG_OFF_FLOATS);

    hipMemsetAsync(flg, 0, 32 * 32 * sizeof(int), stream);
    hipLaunchKernelGGL(wt_kernel, dim3(WG_FLOATS / 256), dim3(256), 0, stream, Whh, wg);

    for (int l = 0; l < L_; ++l) {
        const int K = (l == 0) ? IN_ : H_;
        const float* src = (l == 0) ? x : hbuf;
        const float* Wih = (l == 0) ? Wih0 : (Wihr + (size_t)(l - 1) * G_ * H_);
        const float* Wg_l = wg + (size_t)l * (G_ * H_);
        for (int ch = 0; ch < NCH_; ++ch) {
            const int t0 = ch * TC_;
            const int chkb = (l * NCH_ + ch) * (TC_ - 1);
            hipLaunchKernelGGL(proj_kernel, dim3(1024), dim3(256), 0, stream,
                               src, Wih, bih + l * G_, bhh + l * G_, xp, K, t0);
            hipLaunchKernelGGL(rec8_kernel, dim3(256), dim3(512), 0, stream,
                               xp, Wg_l, hbuf, cbuf, hx, flg, t0, chkb, ch == 0 ? 1 : 0);
        }
    }
    hipLaunchKernelGGL(fc_kernel, dim3(B_), dim3(128), 0, stream, hbuf, fcw, fcb, out);
}